// Round 11
// baseline (402.324 us; speedup 1.0000x reference)
//
#include <hip/hip_runtime.h>
#include <math.h>

#define NB    128   // blocks, 8 batch rows each
#define NT    1024  // 16 waves: 0-7 layer0 (X), 8-15 layer1 (Y)
#define ROWS  8
#define B_TOT 1024
#define T_TOT 512
#define HROW  104   // f16 per h-row (208 B stride; 16B-aligned)
#define XT    32

typedef _Float16 f16;
typedef _Float16 f16x8 __attribute__((ext_vector_type(8)));
typedef float    f32x4 __attribute__((ext_vector_type(4)));

__device__ __forceinline__ float rcp_f(float v){ return __builtin_amdgcn_rcpf(v); }
__device__ __forceinline__ float sig_f(float x){ return rcp_f(1.0f + __expf(-x)); }
__device__ __forceinline__ float tanh_f(float x){ return 1.0f - 2.0f*rcp_f(__expf(2.0f*x) + 1.0f); }

#define MFMA16(a,b,c) __builtin_amdgcn_mfma_f32_16x16x32_f16((a),(b),(c),0,0,0)

__global__ __launch_bounds__(NT, 4) void lstm_wide(
    const float* __restrict__ x,
    const float* __restrict__ h0i, const float* __restrict__ c0i,
    const float* __restrict__ wih0, const float* __restrict__ whh0,
    const float* __restrict__ bih0, const float* __restrict__ bhh0,
    const float* __restrict__ wih1, const float* __restrict__ whh1,
    const float* __restrict__ bih1, const float* __restrict__ bhh1,
    const float* __restrict__ wmean, const float* __restrict__ bmean,
    const float* __restrict__ wcrit, const float* __restrict__ bcrit,
    float* __restrict__ out)
{
    const int tid  = threadIdx.x;
    const int lane = tid & 63;
    const int wv   = tid >> 6;         // 0..15
    const bool isX = (wv < 8);
    const int w    = isX ? wv : (wv - 8);   // wave index within layer group
    const int l15  = lane & 15;
    const int kgrp = lane >> 4;
    const int r0   = blockIdx.x * ROWS;
    const int rl   = l15 & 7;          // B-operand batch row (lanes 8-15 duplicate -> broadcast)
    // A-row decomposition: M row m = qm*4 + ulm (4 gates x 4 units per tile)
    const int qm   = l15 >> 2;         // gate of this lane's A-row
    const int ulm  = l15 & 3;          // unit-sub of A-row
    // cell ownership: 64 cells/wave = 2 tiles x 8 batch x 4 unit-sub
    const int cs   = lane >> 5;        // tile
    const int cb   = (lane >> 2) & 7;  // batch row
    const int cul  = lane & 3;         // unit-sub
    const int cu   = (2*w + cs)*4 + cul;   // owned unit 0..63

    __shared__ __align__(16) f16 hbuf[2][ROWS][HROW];   // rows=batch; cols 0-63 h0, 64-68 x, 69+ 0
    __shared__ __align__(16) f16 ybuf[2][ROWS][HROW];   // rows=batch; cols 0-63 h1
    __shared__ float xt[ROWS][XT][5];
    // wave-private gate bounce: [wave][tile][gate][batch][unit-sub]
    __shared__ __align__(16) float gbuf[16][2][4][ROWS][4];

    // ---- A-fragments (weights, constant in regs) ----
    f16x8 afr[2][4];   // [tile][k-chunk]; X uses 0-2 (+zero), Y uses 0-3
    f32x4 bq[2];       // acc bias init per tile (elements r -> gate kgrp, unit (2w+s)*4+r)
    float cOwn;

    if (isX){
#pragma unroll
        for (int s = 0; s < 2; ++s){
            const int gr = qm*64 + (2*w + s)*4 + ulm;   // weight row for A-row l15
#pragma unroll
            for (int c2 = 0; c2 < 2; ++c2){
                const float* pw = whh0 + (size_t)gr*64 + c2*32 + kgrp*8;
                f16x8 v;
#pragma unroll
                for (int j = 0; j < 8; ++j) v[j] = (f16)pw[j];
                afr[s][c2] = v;
            }
            {   // chunk 2: k 64..95 -> x-weight cols 0..4, rest 0
                f16x8 v;
#pragma unroll
                for (int j = 0; j < 8; ++j){
                    int k = kgrp*8 + j;
                    v[j] = (k < 5) ? (f16)wih0[gr*5 + k] : (f16)0.f;
                }
                afr[s][2] = v;
            }
            afr[s][3] = (f16x8)(f16)0.f;   // unused by X
            f32x4 bb;
#pragma unroll
            for (int r = 0; r < 4; ++r){
                int gu = kgrp*64 + (2*w + s)*4 + r;
                bb[r] = bih0[gu] + bhh0[gu];
            }
            bq[s] = bb;
        }
        cOwn = c0i[(size_t)(r0 + cb)*64 + cu];
    } else {
#pragma unroll
        for (int s = 0; s < 2; ++s){
            const int gr = qm*64 + (2*w + s)*4 + ulm;
#pragma unroll
            for (int c2 = 0; c2 < 2; ++c2){
                const float* pw = wih1 + (size_t)gr*64 + c2*32 + kgrp*8;
                const float* qw = whh1 + (size_t)gr*64 + c2*32 + kgrp*8;
                f16x8 v, u2;
#pragma unroll
                for (int j = 0; j < 8; ++j){ v[j] = (f16)pw[j]; u2[j] = (f16)qw[j]; }
                afr[s][c2]   = v;
                afr[s][2+c2] = u2;
            }
            f32x4 bb;
#pragma unroll
            for (int r = 0; r < 4; ++r){
                int gu = kgrp*64 + (2*w + s)*4 + r;
                bb[r] = bih1[gu] + bhh1[gu];
            }
            bq[s] = bb;
        }
        cOwn = c0i[(size_t)B_TOT*64 + (size_t)(r0 + cb)*64 + cu];
    }

    // ---- LDS init ----
    for (int e = tid; e < 2*ROWS*HROW; e += NT){
        ((f16*)hbuf)[e] = (f16)0.f;
        ((f16*)ybuf)[e] = (f16)0.f;
    }
    __syncthreads();
    if (tid < ROWS*64){
        int cc = tid >> 6, u = tid & 63;
        hbuf[0][cc][u] = (f16)h0i[(size_t)(r0+cc)*64 + u];
        ybuf[1][cc][u] = (f16)h0i[(size_t)B_TOT*64 + (size_t)(r0+cc)*64 + u];
    }
    if (tid < ROWS*5){
        int cc = tid/5, i = tid - cc*5;
        hbuf[0][cc][64+i] = (f16)x[(size_t)(r0+cc)*T_TOT*5 + i];  // x[0]
    }
    for (int e = tid; e < ROWS*XT*5; e += NT){
        int r = e/(XT*5), rem = e - r*(XT*5), ts = rem/5, i = rem - ts*5;
        xt[r][ts][i] = x[((size_t)(r0+r)*T_TOT + ts)*5 + i];      // tile 0
    }
    __syncthreads();

    // ---- 513 pipelined ticks: X = layer0 step t, Y = layer1 step t-1 ----
#pragma unroll 1
    for (int t = 0; t <= T_TOT; ++t){
        const int p = t & 1;

        if ((t+1) < T_TOT && ((t+1) & 31) == 0){      // stage next x tile
            for (int e = tid; e < ROWS*XT*5; e += NT){
                int r = e/(XT*5), rem = e - r*(XT*5), ts = rem/5, i = rem - ts*5;
                xt[r][ts][i] = x[((size_t)(r0+r)*T_TOT + (t+1+ts))*5 + i];
            }
            __syncthreads();
        }
        if ((t+1) < T_TOT && tid < ROWS*5){           // x[t+1] -> next buffer
            int cc = tid/5, i = tid - cc*5;
            hbuf[p^1][cc][64+i] = (f16)xt[cc][(t+1)&31][i];
        }

        if (isX){ if (t < T_TOT){
            const f16* hp = &hbuf[p][rl][kgrp*8];
            f16x8 h0f = *(const f16x8*)(hp);           // k 0..31
            f16x8 h1f = *(const f16x8*)(hp + 32);      // k 32..63
            f16x8 h2f = *(const f16x8*)(hp + 64);      // k 64..95 (x|0)
            f32x4 a0 = bq[0], a1 = bq[1];
            a0 = MFMA16(afr[0][0], h0f, a0);
            a0 = MFMA16(afr[0][1], h1f, a0);
            a0 = MFMA16(afr[0][2], h2f, a0);
            a1 = MFMA16(afr[1][0], h0f, a1);
            a1 = MFMA16(afr[1][1], h1f, a1);
            a1 = MFMA16(afr[1][2], h2f, a1);
            if (l15 < ROWS){
                *(f32x4*)&gbuf[wv][0][kgrp][l15][0] = a0;
                *(f32x4*)&gbuf[wv][1][kgrp][l15][0] = a1;
            }
            // cell update: 1 cell/lane (in-order DS guarantees write->read)
            float gi = gbuf[wv][cs][0][cb][cul];
            float gf = gbuf[wv][cs][1][cb][cul];
            float gg = gbuf[wv][cs][2][cb][cul];
            float go = gbuf[wv][cs][3][cb][cul];
            cOwn = sig_f(gf)*cOwn + sig_f(gi)*tanh_f(gg);
            hbuf[p^1][cb][cu] = (f16)(sig_f(go)*tanh_f(cOwn));
        }} else { if (t >= 1){
            const f16* hp = &hbuf[p][rl][kgrp*8];
            f16x8 h0f = *(const f16x8*)(hp);           // h0_new k 0..31
            f16x8 h1f = *(const f16x8*)(hp + 32);      // h0_new k 32..63
            const f16* yp = &ybuf[p][rl][kgrp*8];
            f16x8 y0f = *(const f16x8*)(yp);           // h1_old k 0..31
            f16x8 y1f = *(const f16x8*)(yp + 32);      // h1_old k 32..63
            f32x4 a0 = bq[0], a1 = bq[1];
            a0 = MFMA16(afr[0][0], h0f, a0);
            a0 = MFMA16(afr[0][1], h1f, a0);
            a0 = MFMA16(afr[0][2], y0f, a0);
            a0 = MFMA16(afr[0][3], y1f, a0);
            a1 = MFMA16(afr[1][0], h0f, a1);
            a1 = MFMA16(afr[1][1], h1f, a1);
            a1 = MFMA16(afr[1][2], y0f, a1);
            a1 = MFMA16(afr[1][3], y1f, a1);
            if (l15 < ROWS){
                *(f32x4*)&gbuf[wv][0][kgrp][l15][0] = a0;
                *(f32x4*)&gbuf[wv][1][kgrp][l15][0] = a1;
            }
            float gi = gbuf[wv][cs][0][cb][cul];
            float gf = gbuf[wv][cs][1][cb][cul];
            float gg = gbuf[wv][cs][2][cb][cul];
            float go = gbuf[wv][cs][3][cb][cul];
            cOwn = sig_f(gf)*cOwn + sig_f(gi)*tanh_f(gg);
            ybuf[p^1][cb][cu] = (f16)(sig_f(go)*tanh_f(cOwn));
        }}
        __syncthreads();
    }

    // ---- heads: final h1 = ybuf[1] (tick 512, p=0, wrote p^1=1) ----
    if (wv < ROWS){
        const int cc = wv, u = lane;
        float hr = (float)ybuf[1][cc][u];
        float pm = hr * wmean[u];
        float pc = hr * wcrit[u];
#pragma unroll
        for (int o = 32; o > 0; o >>= 1){
            pm += __shfl_down(pm, o);
            pc += __shfl_down(pc, o);
        }
        if (u == 0){
            float m = pm + bmean[0];
            out[r0+cc]           = 2.f*tanh_f(m);
            out[B_TOT + r0+cc]   = __logf(1.f + __expf(m));
            out[2*B_TOT + r0+cc] = pc + bcrit[0];
        }
    }
}

extern "C" void kernel_launch(void* const* d_in, const int* in_sizes, int n_in,
                              void* d_out, int out_size, void* d_ws, size_t ws_size,
                              hipStream_t stream) {
    const float* x     = (const float*)d_in[0];
    const float* h0i   = (const float*)d_in[1];
    const float* c0i   = (const float*)d_in[2];
    const float* wih0  = (const float*)d_in[3];
    const float* whh0  = (const float*)d_in[4];
    const float* bih0  = (const float*)d_in[5];
    const float* bhh0  = (const float*)d_in[6];
    const float* wih1  = (const float*)d_in[7];
    const float* whh1  = (const float*)d_in[8];
    const float* bih1  = (const float*)d_in[9];
    const float* bhh1  = (const float*)d_in[10];
    const float* wmean = (const float*)d_in[11];
    const float* bmean = (const float*)d_in[12];
    const float* wcrit = (const float*)d_in[13];
    const float* bcrit = (const float*)d_in[14];

    lstm_wide<<<NB, NT, 0, stream>>>(x, h0i, c0i, wih0, whh0, bih0, bhh0,
                                     wih1, whh1, bih1, bhh1,
                                     wmean, bmean, wcrit, bcrit,
                                     (float*)d_out);
}